// Round 1
// baseline (806.681 us; speedup 1.0000x reference)
//
#include <hip/hip_runtime.h>
#include <hip/hip_bf16.h>
#include <cstdint>
#include <cstddef>

typedef unsigned short u16;
typedef __attribute__((ext_vector_type(8))) __bf16 bf16x8;
typedef __attribute__((ext_vector_type(4))) float f32x4;

#define EPS_BN 1e-5f

__device__ __forceinline__ u16 f2bf(float f) {
    union { float f; uint32_t u; } v; v.f = f;
    uint32_t u = v.u;
    u += 0x7FFFu + ((u >> 16) & 1u);   // round-to-nearest-even
    return (u16)(u >> 16);
}
__device__ __forceinline__ float bf2f(u16 s) {
    union { uint32_t u; float f; } v; v.u = ((uint32_t)s) << 16;
    return v.f;
}

union Pack8 { u16 u[8]; uint4 v4; };

// ---------------------------------------------------------------------------
// Implicit-im2col GEMM:  out[oc, (b,oy,ox)] = sum_k W[oc,k] * X[k,(b,oy,ox)]
// K ordered (tap, c): W prepped as [oc][tap][c] bf16. NCHW activations.
// 128x128 tile, BK=64, 4 waves, each wave 4x4 frags of 16x16x32 bf16 MFMA.
// LDS: A[row=oc][k], B[row=j][k], XOR-swizzled 16B chunks (2-way banks, free).
// grid: x = I-tile (0..1), y = J-tile.  Jtotal must be a multiple of 128.
// ---------------------------------------------------------------------------
template<int TAPS, typename InT, typename OutT, bool RELU>
__global__ __launch_bounds__(256)
void conv_gemm(const InT* __restrict__ in, const u16* __restrict__ W,
               const float* __restrict__ scale, const float* __restrict__ shift,
               OutT* __restrict__ out, int Hi, int Wi, int Ho, int Wo)
{
    constexpr int KT = TAPS * 256;
    constexpr int KB = KT / 64;
    const int HoWo = Ho * Wo;
    const int HiWi = Hi * Wi;

    __shared__ u16 Alds[128 * 64];
    __shared__ u16 Blds[128 * 64];

    const int tid = threadIdx.x;
    const int it = blockIdx.x;   // I tile (oc): 0..1
    const int jt = blockIdx.y;   // J tile

    // ---- B staging coords (thread -> fixed output column, walks channels)
    const int jl = tid & 127;
    const int kh = tid >> 7;           // which 32-k half
    const int jg = jt * 128 + jl;
    const int bb = jg / HoWo;
    const int msp = jg - bb * HoWo;
    const int oy = msp / Wo;
    const int ox = msp - oy * Wo;
    const InT* inb = in + (size_t)bb * 256 * HiWi + (size_t)oy * Wi + ox;

    // ---- MFMA coords
    const int lane = tid & 63;
    const int wv = tid >> 6;
    const int wi = (wv >> 1) * 64;     // wave's I offset in tile
    const int wj = (wv & 1) * 64;      // wave's J offset in tile
    const int lr = lane & 15;
    const int lq = lane >> 4;

    f32x4 acc[4][4];
    #pragma unroll
    for (int a = 0; a < 4; a++)
        #pragma unroll
        for (int b = 0; b < 4; b++)
            acc[a][b] = (f32x4){0.f, 0.f, 0.f, 0.f};

    for (int kb = 0; kb < KB; kb++) {
        const int tap = (TAPS == 1) ? 0 : (kb >> 2);
        const int c0  = (TAPS == 1) ? (kb * 64) : ((kb & 3) * 64);
        __syncthreads();
        // ---- stage A (weights): 128 rows x 64 k, 16B chunks
        {
            const u16* Wb = W + (size_t)(it * 128) * KT + tap * 256 + c0;
            #pragma unroll
            for (int q = 0; q < 4; q++) {
                int g = q * 256 + tid;
                int row = g >> 3, cc = g & 7;
                uint4 v = *(const uint4*)(Wb + (size_t)row * KT + cc * 8);
                *(uint4*)&Alds[row * 64 + ((cc ^ (row & 7)) * 8)] = v;
            }
        }
        // ---- stage B (activations, implicit im2col, transpose into [j][k])
        {
            int ky = 0, kx = 0;
            if (TAPS == 9) { ky = tap / 3; kx = tap - ky * 3; }
            const InT* p0 = inb + (size_t)(c0 + kh * 32) * HiWi + ky * Wi + kx;
            #pragma unroll
            for (int c4 = 0; c4 < 4; c4++) {
                Pack8 p;
                #pragma unroll
                for (int i = 0; i < 8; i++) {
                    size_t off = (size_t)(c4 * 8 + i) * HiWi;
                    if constexpr (sizeof(InT) == 4) p.u[i] = f2bf((float)p0[off]);
                    else                            p.u[i] = (u16)p0[off];
                }
                int ck = kh * 4 + c4;
                *(uint4*)&Blds[jl * 64 + ((ck ^ (jl & 7)) * 8)] = p.v4;
            }
        }
        __syncthreads();
        // ---- MFMA: 2 k-steps of 32
        #pragma unroll
        for (int ks = 0; ks < 2; ks++) {
            bf16x8 af[4], bfr[4];
            const int ck = ks * 4 + lq;
            #pragma unroll
            for (int f = 0; f < 4; f++) {
                int ra = wi + f * 16 + lr;
                af[f]  = *(const bf16x8*)&Alds[ra * 64 + ((ck ^ (ra & 7)) * 8)];
                int rb = wj + f * 16 + lr;
                bfr[f] = *(const bf16x8*)&Blds[rb * 64 + ((ck ^ (rb & 7)) * 8)];
            }
            #pragma unroll
            for (int fi = 0; fi < 4; fi++)
                #pragma unroll
                for (int fj = 0; fj < 4; fj++)
                    acc[fi][fj] = __builtin_amdgcn_mfma_f32_16x16x32_bf16(
                        af[fi], bfr[fj], acc[fi][fj], 0, 0, 0);
        }
    }

    // ---- epilogue: BN (scale/shift) + optional ReLU, write NCHW
    int jcb[4], jcm[4];
    #pragma unroll
    for (int fj = 0; fj < 4; fj++) {
        int jc = jt * 128 + wj + fj * 16 + lr;
        int b = jc / HoWo;
        jcb[fj] = b; jcm[fj] = jc - b * HoWo;
    }
    #pragma unroll
    for (int fi = 0; fi < 4; fi++) {
        int rb = it * 128 + wi + fi * 16 + lq * 4;
        f32x4 sc = *(const f32x4*)&scale[rb];
        f32x4 sh = *(const f32x4*)&shift[rb];
        #pragma unroll
        for (int reg = 0; reg < 4; reg++) {
            int r = rb + reg;
            #pragma unroll
            for (int fj = 0; fj < 4; fj++) {
                float v = acc[fi][fj][reg] * sc[reg] + sh[reg];
                if (RELU) v = fmaxf(v, 0.f);
                size_t o = ((size_t)(jcb[fj] * 256 + r)) * HoWo + jcm[fj];
                if constexpr (sizeof(OutT) == 2) ((u16*)out)[o] = f2bf(v);
                else                             out[o] = v;
            }
        }
    }
}

// ---------------------------------------------------------------------------
// Depthwise cross-correlation: feat[b,c,y,x] = sum_{5x5} s[b,c,y+dy,x+dx]*k[b,c,dy,dx]
// one block per (b,c) plane
// ---------------------------------------------------------------------------
__global__ __launch_bounds__(256)
void xcorr_kernel(const u16* __restrict__ s, const u16* __restrict__ k,
                  u16* __restrict__ out)
{
    __shared__ float sl[841];
    __shared__ float kl[25];
    const int plane = blockIdx.x;
    const u16* sp = s + (size_t)plane * 841;
    const u16* kp = k + (size_t)plane * 25;
    const int tid = threadIdx.x;
    for (int i = tid; i < 841; i += 256) sl[i] = bf2f(sp[i]);
    if (tid < 25) kl[tid] = bf2f(kp[tid]);
    __syncthreads();
    for (int m = tid; m < 625; m += 256) {
        int y = m / 25, x = m - y * 25;
        float a = 0.f;
        #pragma unroll
        for (int dy = 0; dy < 5; dy++)
            #pragma unroll
            for (int dx = 0; dx < 5; dx++)
                a += sl[(y + dy) * 29 + (x + dx)] * kl[dy * 5 + dx];
        out[(size_t)plane * 625 + m] = f2bf(a);
    }
}

// ---------------------------------------------------------------------------
// Weight prep: OIHW fp32 -> [oc][tap][c] bf16 (3x3) / direct convert (1x1)
// ---------------------------------------------------------------------------
__global__ void prep_w3(const float* __restrict__ w, u16* __restrict__ o)
{
    int idx = blockIdx.x * 256 + threadIdx.x;
    if (idx >= 256 * 2304) return;
    int oc = idx / 2304, rem = idx - oc * 2304;
    int tap = rem >> 8, c = rem & 255;
    o[idx] = f2bf(w[oc * 2304 + c * 9 + tap]);
}
__global__ void prep_w1(const float* __restrict__ w, u16* __restrict__ o)
{
    int idx = blockIdx.x * 256 + threadIdx.x;
    if (idx < 65536) o[idx] = f2bf(w[idx]);
}
__global__ void prep_bn(const float* gk, const float* bk, const float* mk, const float* vk,
                        const float* gs, const float* bs, const float* ms, const float* vs,
                        const float* gh, const float* bh, const float* mh, const float* vh,
                        const float* bh2,
                        float* sk, float* tk, float* ss, float* ts,
                        float* sh, float* th, float* s5, float* t5)
{
    int i = threadIdx.x;
    float iv;
    iv = rsqrtf(vk[i] + EPS_BN) * gk[i]; sk[i] = iv; tk[i] = bk[i] - mk[i] * iv;
    iv = rsqrtf(vs[i] + EPS_BN) * gs[i]; ss[i] = iv; ts[i] = bs[i] - ms[i] * iv;
    iv = rsqrtf(vh[i] + EPS_BN) * gh[i]; sh[i] = iv; th[i] = bh[i] - mh[i] * iv;
    s5[i] = 1.f; t5[i] = bh2[i];
}

// ---------------------------------------------------------------------------
extern "C" void kernel_launch(void* const* d_in, const int* in_sizes, int n_in,
                              void* d_out, int out_size, void* d_ws, size_t ws_size,
                              hipStream_t stream)
{
    const float* in_kernel = (const float*)d_in[0];
    const float* in_search = (const float*)d_in[1];
    const float* wk  = (const float*)d_in[2];
    const float* gk  = (const float*)d_in[3];
    const float* bk  = (const float*)d_in[4];
    const float* mk  = (const float*)d_in[5];
    const float* vk  = (const float*)d_in[6];
    const float* wsw = (const float*)d_in[7];
    const float* gs  = (const float*)d_in[8];
    const float* bs  = (const float*)d_in[9];
    const float* ms  = (const float*)d_in[10];
    const float* vs  = (const float*)d_in[11];
    const float* wh1 = (const float*)d_in[12];
    const float* gh  = (const float*)d_in[13];
    const float* bh  = (const float*)d_in[14];
    const float* mh  = (const float*)d_in[15];
    const float* vh  = (const float*)d_in[16];
    const float* wh2 = (const float*)d_in[17];
    const float* bh2 = (const float*)d_in[18];
    float* out = (float*)d_out;

    char* w = (char*)d_ws;
    u16* Wk2 = (u16*)w;  w += 1179648;      // 256*2304 bf16
    u16* Ws2 = (u16*)w;  w += 1179648;
    u16* Wh1 = (u16*)w;  w += 131072;       // 256*256 bf16
    u16* Wh2 = (u16*)w;  w += 131072;
    float* sk = (float*)w; w += 1024;
    float* tk = (float*)w; w += 1024;
    float* ss = (float*)w; w += 1024;
    float* ts = (float*)w; w += 1024;
    float* sh = (float*)w; w += 1024;
    float* th = (float*)w; w += 1024;
    float* s5 = (float*)w; w += 1024;
    float* t5 = (float*)w; w += 1024;
    u16* kfeat = (u16*)w; w += 1638400;     // 128*256*25 bf16
    u16* sfeat = (u16*)w; w += 55115776;    // 128*256*841 bf16
    u16* feat  = (u16*)w; w += 40960000;    // 128*256*625 bf16
    u16* hbuf  = (u16*)w; w += 40960000;    // 128*256*625 bf16

    prep_w3<<<2304, 256, 0, stream>>>(wk,  Wk2);
    prep_w3<<<2304, 256, 0, stream>>>(wsw, Ws2);
    prep_w1<<<256, 256, 0, stream>>>(wh1, Wh1);
    prep_w1<<<256, 256, 0, stream>>>(wh2, Wh2);
    prep_bn<<<1, 256, 0, stream>>>(gk, bk, mk, vk, gs, bs, ms, vs, gh, bh, mh, vh,
                                   bh2, sk, tk, ss, ts, sh, th, s5, t5);

    // stage 1: kernel tower  [128,256,7,7] -> [128,256,5,5]   J=3200 -> 25 tiles
    conv_gemm<9, float, u16, true><<<dim3(2, 25), 256, 0, stream>>>(
        in_kernel, Wk2, sk, tk, kfeat, 7, 7, 5, 5);
    // stage 2: search tower  [128,256,31,31] -> [128,256,29,29]  J=107648 -> 841 tiles
    conv_gemm<9, float, u16, true><<<dim3(2, 841), 256, 0, stream>>>(
        in_search, Ws2, ss, ts, sfeat, 31, 31, 29, 29);
    // stage 3: depthwise xcorr -> [128,256,25,25]
    xcorr_kernel<<<128 * 256, 256, 0, stream>>>(sfeat, kfeat, feat);
    // stage 4: head 1x1 + BN + ReLU   J=80000 -> 625 tiles
    conv_gemm<1, u16, u16, true><<<dim3(2, 625), 256, 0, stream>>>(
        feat, Wh1, sh, th, hbuf, 25, 25, 25, 25);
    // stage 5: head 1x1 + bias (no relu), fp32 out
    conv_gemm<1, u16, float, false><<<dim3(2, 625), 256, 0, stream>>>(
        hbuf, Wh2, s5, t5, out, 25, 25, 25, 25);

    (void)in_sizes; (void)n_in; (void)out_size; (void)ws_size;
}